// Round 8
// baseline (1079.695 us; speedup 1.0000x reference)
//
#include <hip/hip_runtime.h>

// SingleSiteMinimizer, fp16-MFMA pipeline:
//   G1: T1[k][(lt,w)][(p,r)] = envL_k(tile) @ A     } merged dual-grid dispatch
//   G3: Y'[(lt,P)][k*4096+(v,r)] = A(tile) @ envR^T } (blockIdx.z)
//   G4: out += sum_k sum_{m,n} (T1_k Y'_k^T)[m,n] * W2pref[k][n][m]  (fused trace)
//   out /= sum(A^2)
// Round 8: 8-phase (4/K-tile) interleaved schedule for gemm_dual256 per m201
// template: per phase {ds_read subtile ; stage 1 half-tile ; barrier ; lgkmcnt(0);
// setprio(1); 16 MFMA; setprio(0); barrier}, counted vmcnt(4) once per K-tile.
// LDS layout [buf][A|B][kh][256][32] so half-tiles are contiguous 16KB slabs.

typedef __attribute__((ext_vector_type(8))) _Float16 f16x8;
typedef __attribute__((ext_vector_type(4))) float f32x4;

__device__ __forceinline__ unsigned short f2h(float f) {
    _Float16 h = (_Float16)f;
    return *(unsigned short*)&h;
}

__device__ __forceinline__ void gload16(const void* g, void* l) {
    __builtin_amdgcn_global_load_lds(
        (const __attribute__((address_space(1))) void*)g,
        (__attribute__((address_space(3))) void*)l, 16, 0, 0);
}

struct GArg {
    const unsigned short* A;
    const unsigned short* B;
    unsigned short* C;
    int kshift;        // A row slab shift (30 => none)
    long long kextra;  // extra elems per slab
};

// Stage one 16KB k-half slab (A or B) of K-tile tt into buf[tt&1].
// LDS slot s (16B) = row*4 + kg holds global k-chunk kg ^ ((row>>1)&3)  [rule 21].
__device__ __forceinline__ void stage_half(
    const GArg& g, short* lds, int row0, int col0, int tid,
    int tt, int kh, int isB)
{
    short* dst = lds + (tt & 1) * 32768 + isB * 16384 + kh * 8192;
    const unsigned short* src = isB ? g.B : g.A;
    #pragma unroll
    for (int q = 0; q < 2; ++q) {
        const int s = q * 512 + tid;
        const int row = s >> 2;
        const int kgs = (s & 3) ^ ((row >> 1) & 3);
        size_t off;
        if (isB) {
            off = (size_t)(col0 + row) * 512 + tt * 64 + kh * 32 + kgs * 8;
        } else {
            const int gr = row0 + row;
            off = (size_t)gr * 512 + (size_t)((unsigned)gr >> g.kshift) * g.kextra
                + tt * 64 + kh * 32 + kgs * 8;
        }
        gload16(src + off, dst + s * 8);
    }
}

#define PHASE_SYNC_IN() do { \
    __builtin_amdgcn_sched_barrier(0); \
    __builtin_amdgcn_s_barrier(); \
    asm volatile("s_waitcnt lgkmcnt(0)" ::: "memory"); \
    __builtin_amdgcn_sched_barrier(0); \
} while (0)

#define PHASE_SYNC_OUT() do { \
    __builtin_amdgcn_sched_barrier(0); \
    __builtin_amdgcn_s_barrier(); \
    __builtin_amdgcn_sched_barrier(0); \
} while (0)

#define MFMA16(base) do { \
    __builtin_amdgcn_s_setprio(1); \
    _Pragma("unroll") \
    for (int ii = 0; ii < 4; ++ii) \
        _Pragma("unroll") \
        for (int j = 0; j < 4; ++j) \
            acc[(base) + ii][j] = __builtin_amdgcn_mfma_f32_16x16x32_f16( \
                afr[ii], bfr[j], acc[(base) + ii][j], 0, 0, 0); \
    __builtin_amdgcn_s_setprio(0); \
} while (0)

// ---------- 256x256 dual fp16 GEMM: C[M,N] = Aop[M,K] x Bop[N,K]^T ----------
// lda=ldb=512, ldc=16384. gridDim.x MUST be 64 (col panels), XCD-pinned.
__global__ __launch_bounds__(512, 1) void gemm_dual256(int K, GArg g0, GArg g1)
{
    __shared__ short lds[65536];  // 128 KB: [buf][A|B][kh][256][32]
    const GArg g = blockIdx.z ? g1 : g0;
    const int tid = threadIdx.x;
    const int wid = tid >> 6, lane = tid & 63;
    const int wm = wid >> 2, wn = wid & 3;          // 2M x 4N waves
    const int lrow = lane & 15, lgrp = lane >> 4;
    // fragment read offset within a [256][32] slab (shorts); 2-way-free swizzle
    const int rdoff = lrow * 32 + (lgrp ^ ((lrow >> 1) & 3)) * 8;

    // XCD-pinned mapping: xcd owns 8 consecutive col panels (2 MB L2 hot-set)
    const int flat = blockIdx.y * 64 + blockIdx.x;
    const int xcd = flat & 7, local = flat >> 3;
    const int col0 = (xcd * 8 + (local & 7)) * 256;
    const int row0 = (local >> 3) * 256;

    const int nt = K >> 6;                          // 8 K-tiles of 64

    f32x4 acc[8][4] = {};

    // prologue: tile0 fully, tile1 kh0. vmcnt(4) => tile0 landed, tile1-kh0 in flight
    stage_half(g, lds, row0, col0, tid, 0, 0, 0);
    stage_half(g, lds, row0, col0, tid, 0, 0, 1);
    stage_half(g, lds, row0, col0, tid, 0, 1, 0);
    stage_half(g, lds, row0, col0, tid, 0, 1, 1);
    stage_half(g, lds, row0, col0, tid, 1, 0, 0);
    stage_half(g, lds, row0, col0, tid, 1, 0, 1);
    asm volatile("s_waitcnt vmcnt(4)" ::: "memory");
    __builtin_amdgcn_s_barrier();
    __builtin_amdgcn_sched_barrier(0);

    for (int t = 0; t < nt; ++t) {
        const short* aslab0 = lds + (t & 1) * 32768;
        const short* aslab1 = aslab0 + 8192;
        const short* bslab0 = aslab0 + 16384;
        const short* bslab1 = bslab0 + 8192;
        f16x8 afr[4], bfr[4];

        // ---- phase 0: kh0, rows lo. reads: 4 B + 4 A. stage: A-kh1(t+1)
        #pragma unroll
        for (int j = 0; j < 4; ++j)
            bfr[j] = *(const f16x8*)(bslab0 + (wn * 64 + j * 16) * 32 + rdoff);
        #pragma unroll
        for (int ii = 0; ii < 4; ++ii)
            afr[ii] = *(const f16x8*)(aslab0 + (wm * 128 + ii * 16) * 32 + rdoff);
        if (t + 1 < nt) stage_half(g, lds, row0, col0, tid, t + 1, 1, 0);
        PHASE_SYNC_IN();
        MFMA16(0);
        PHASE_SYNC_OUT();

        // ---- phase 1: kh0, rows hi. reads: 4 A. stage: B-kh1(t+1)
        #pragma unroll
        for (int ii = 0; ii < 4; ++ii)
            afr[ii] = *(const f16x8*)(aslab0 + (wm * 128 + 64 + ii * 16) * 32 + rdoff);
        if (t + 1 < nt) stage_half(g, lds, row0, col0, tid, t + 1, 1, 1);
        PHASE_SYNC_IN();
        MFMA16(4);
        PHASE_SYNC_OUT();

        // ---- phase 2: kh1, rows lo. reads: 4 B + 4 A. stage: A-kh0(t+2)
        #pragma unroll
        for (int j = 0; j < 4; ++j)
            bfr[j] = *(const f16x8*)(bslab1 + (wn * 64 + j * 16) * 32 + rdoff);
        #pragma unroll
        for (int ii = 0; ii < 4; ++ii)
            afr[ii] = *(const f16x8*)(aslab1 + (wm * 128 + ii * 16) * 32 + rdoff);
        if (t + 2 < nt) stage_half(g, lds, row0, col0, tid, t + 2, 0, 0);
        PHASE_SYNC_IN();
        MFMA16(0);
        PHASE_SYNC_OUT();

        // ---- phase 3: kh1, rows hi. reads: 4 A. stage: B-kh0(t+2)
        #pragma unroll
        for (int ii = 0; ii < 4; ++ii)
            afr[ii] = *(const f16x8*)(aslab1 + (wm * 128 + 64 + ii * 16) * 32 + rdoff);
        if (t + 2 < nt) stage_half(g, lds, row0, col0, tid, t + 2, 0, 1);
        PHASE_SYNC_IN();
        MFMA16(4);
        // end-of-tile counted wait: tile t+1 fully landed, t+2's 4 loads in flight
        __builtin_amdgcn_sched_barrier(0);
        if (t + 2 < nt) asm volatile("s_waitcnt vmcnt(4)" ::: "memory");
        else            asm volatile("s_waitcnt vmcnt(0)" ::: "memory");
        PHASE_SYNC_OUT();
    }

    // epilogue: repack through LDS (stride 264 shorts), int4 coalesced stores
    const int orow = lgrp * 4, ocol = lrow;
    __syncthreads();
    #pragma unroll
    for (int h = 0; h < 2; ++h) {
        if (wm == h) {
            #pragma unroll
            for (int i = 0; i < 8; ++i)
                #pragma unroll
                for (int j = 0; j < 4; ++j)
                    #pragma unroll
                    for (int q = 0; q < 4; ++q)
                        lds[(i * 16 + orow + q) * 264 + wn * 64 + j * 16 + ocol] =
                            (short)f2h(acc[i][j][q]);
        }
        __syncthreads();
        #pragma unroll
        for (int s2 = 0; s2 < 8; ++s2) {
            const int ch = s2 * 512 + tid;
            const int rr = ch >> 5, c16 = ch & 31;
            *(int4*)(g.C + (size_t)(row0 + h * 128 + rr) * 16384 + col0 + c16 * 8) =
                *(const int4*)&lds[rr * 264 + c16 * 8];
        }
        __syncthreads();
    }
}

// ---------- G4: 1024-thread blocks, full 256x256 output, exactly-once reads ----------
__global__ __launch_bounds__(1024) void gemm_g4w(
    const unsigned short* __restrict__ T1, const unsigned short* __restrict__ Yp,
    const float* __restrict__ W2p, float* __restrict__ dacc,
    int Lt8, int zkShift, int BKC)
{
    __shared__ short sh[16384];  // As = sh[0:8192], Bs = sh[8192:16384]
    const int tid = threadIdx.x;
    const int wid = tid >> 6, lane = tid & 63;
    const int kidx = blockIdx.x >> zkShift;
    const int kz = (blockIdx.x - (kidx << zkShift)) * BKC;
    const int wr = (wid >> 2) * 64, wc = (wid & 3) * 64;
    const int lrow = lane & 15, kb = (lane >> 4) * 8;

    const int r = tid >> 2, kc = (tid & 3) * 8;  // staging: row 0..255
    const int w_ = r >> 5, p_ = r & 31;
    const size_t T1k = (size_t)kidx * Lt8 * 16384;
    const size_t Yk = (size_t)kidx * 4096;
    const size_t aoff = T1k + (size_t)w_ * 16384 + (size_t)p_ * 512;   // + lt*131072 + rr
    const size_t boff = Yk + (size_t)p_ * 16384 + (size_t)w_ * 512;    // (v=w_, P=p_)

    f32x4 acc[4][4] = {};

    for (int k0 = 0; k0 < BKC; k0 += 32) {
        const int kk = kz + k0;
        const int lt = kk >> 9, rbase = kk & 511;
        gload16(T1 + aoff + (size_t)lt * 131072 + rbase + kc, sh + tid * 8);
        gload16(Yp + boff + (size_t)lt * 524288 + rbase + kc, sh + 8192 + tid * 8);
        __syncthreads();
        f16x8 a[4], b[4];
        #pragma unroll
        for (int i = 0; i < 4; ++i)
            a[i] = *(const f16x8*)&sh[(wr + i * 16 + lrow) * 32 + kb];
        #pragma unroll
        for (int j = 0; j < 4; ++j)
            b[j] = *(const f16x8*)&sh[8192 + (wc + j * 16 + lrow) * 32 + kb];
        #pragma unroll
        for (int i = 0; i < 4; ++i)
            #pragma unroll
            for (int j = 0; j < 4; ++j)
                acc[i][j] = __builtin_amdgcn_mfma_f32_16x16x32_f16(a[i], b[j], acc[i][j], 0, 0, 0);
        __syncthreads();
    }

    // fused weighted trace
    const int orow = (lane >> 4) * 4, ocol = lane & 15;
    const float* Wk = W2p + ((size_t)kidx << 16);
    float s = 0.f;
    #pragma unroll
    for (int j = 0; j < 4; ++j) {
        const int n = wc + j * 16 + ocol;
        const float* wrow = Wk + (size_t)n * 256 + wr + orow;
        #pragma unroll
        for (int i = 0; i < 4; ++i) {
            float4 wv = *(const float4*)(wrow + i * 16);
            s += wv.x * acc[i][j][0] + wv.y * acc[i][j][1]
               + wv.z * acc[i][j][2] + wv.w * acc[i][j][3];
        }
    }
    __syncthreads();
    float* red = (float*)sh;
    red[tid] = s;
    __syncthreads();
    for (int st = 512; st > 0; st >>= 1) {
        if (tid < st) red[tid] += red[tid + st];
        __syncthreads();
    }
    if (tid == 0) atomicAdd(dacc, red[0]);
}

// ---------- prep kernels ----------
__global__ __launch_bounds__(256) void cast_sumsq(
    const float* __restrict__ in, unsigned short* __restrict__ out,
    long long n4, float* __restrict__ sumsq)
{
    float p = 0.f;
    for (long long i = (long long)blockIdx.x * blockDim.x + threadIdx.x; i < n4;
         i += (long long)gridDim.x * blockDim.x) {
        float4 v = ((const float4*)in)[i];
        p += v.x * v.x + v.y * v.y + v.z * v.z + v.w * v.w;
        union { unsigned short s[4]; uint2 d; } o;
        o.s[0] = f2h(v.x); o.s[1] = f2h(v.y); o.s[2] = f2h(v.z); o.s[3] = f2h(v.w);
        ((uint2*)out)[i] = o.d;
    }
    __shared__ float sh[256];
    sh[threadIdx.x] = p;
    __syncthreads();
    for (int s = 128; s > 0; s >>= 1) {
        if (threadIdx.x < s) sh[threadIdx.x] += sh[threadIdx.x + s];
        __syncthreads();
    }
    if (threadIdx.x == 0) atomicAdd(sumsq, sh[0]);
}

__global__ void cast_kernel(const float* __restrict__ in, unsigned short* __restrict__ out,
                            long long n4)
{
    for (long long i = (long long)blockIdx.x * blockDim.x + threadIdx.x; i < n4;
         i += (long long)gridDim.x * blockDim.x) {
        float4 v = ((const float4*)in)[i];
        union { unsigned short s[4]; uint2 d; } o;
        o.s[0] = f2h(v.x); o.s[1] = f2h(v.y); o.s[2] = f2h(v.z); o.s[3] = f2h(v.w);
        ((uint2*)out)[i] = o.d;
    }
}

__global__ void transpose_cast(const float* __restrict__ in, unsigned short* __restrict__ out,
                               int R, int C, long long in_stride, long long out_stride)
{
    __shared__ float tile[32][33];
    in += (long long)blockIdx.z * in_stride;
    out += (long long)blockIdx.z * out_stride;
    int c0 = blockIdx.x * 32, r0 = blockIdx.y * 32;
    int tx = threadIdx.x, ty = threadIdx.y;  // (32, 8)
    #pragma unroll
    for (int i = 0; i < 4; ++i)
        tile[ty + i * 8][tx] = in[(size_t)(r0 + ty + i * 8) * C + c0 + tx];
    __syncthreads();
    #pragma unroll
    for (int i = 0; i < 4; ++i)
        out[(size_t)(c0 + ty + i * 8) * R + r0 + tx] = f2h(tile[tx][ty + i * 8]);
}

__global__ void build_ops(const float* __restrict__ theta, float* __restrict__ ops)
{
    __shared__ float X[32][32], Pm[32][32];
    int i = threadIdx.y, j = threadIdx.x;
    float c = cosf(theta[0]), s = sinf(theta[0]);
    float aij = (j == i + 1) ? sqrtf((float)j) : 0.f;
    float aji = (i == j + 1) ? sqrtf((float)i) : 0.f;
    const float inv = 0.70710678118654752440f;
    float x0 = (aij + aji) * inv;
    float p0 = (aij - aji) * inv;
    X[i][j] = c * x0 + s * p0;
    Pm[i][j] = -s * x0 + c * p0;
    __syncthreads();
    float xx = 0.f, pp = 0.f;
    #pragma unroll
    for (int m = 0; m < 32; ++m) {
        xx += X[i][m] * X[m][j];
        pp += Pm[i][m] * Pm[m][j];
    }
    ops[0 * 1024 + i * 32 + j] = (i == j) ? 1.f : 0.f;
    ops[1 * 1024 + i * 32 + j] = X[i][j];
    ops[2 * 1024 + i * 32 + j] = Pm[i][j];
    ops[3 * 1024 + i * 32 + j] = xx;
    ops[4 * 1024 + i * 32 + j] = pp;
}

// W2p[k][(v*32+P)*256 + (w*32+p)] = pref[k] * sum_c coeffs[k,w,v,c] * ops[c][P,p]
__global__ void build_w(const float* __restrict__ coeffs, const float* __restrict__ ops,
                        const float* __restrict__ pref, float* __restrict__ W2)
{
    int b = blockIdx.x;  // (k,w,v)
    int k = b >> 6, w = (b >> 3) & 7, v = b & 7;
    int P = threadIdx.y, p = threadIdx.x;
    const float* cf = coeffs + ((k * 8 + w) * 8 + v) * 5;
    float acc = 0.f;
    #pragma unroll
    for (int c = 0; c < 5; ++c) acc += cf[c] * ops[c * 1024 + P * 32 + p];
    W2[(size_t)k * 65536 + (v * 32 + P) * 256 + (w * 32 + p)] = acc * pref[k];
}

__global__ void finalize_kernel(const float* __restrict__ dacc, const float* __restrict__ sumsq,
                                float* __restrict__ out)
{
    if (threadIdx.x == 0) out[0] = dacc[0] / sumsq[0];
}

extern "C" void kernel_launch(void* const* d_in, const int* in_sizes, int n_in,
                              void* d_out, int out_size, void* d_ws, size_t ws_size,
                              hipStream_t stream)
{
    const float* A      = (const float*)d_in[0];  // [512,32,512]
    const float* theta  = (const float*)d_in[1];
    const float* envL   = (const float*)d_in[2];  // [4,512,8,512]
    const float* envR   = (const float*)d_in[3];  // [4,512,8,512]
    const float* coeffs = (const float*)d_in[4];  // [4,8,8,5]
    const float* pref   = (const float*)d_in[5];  // [4]
    float* out = (float*)d_out;

    char* ws = (char*)d_ws;
    float* sumsq = (float*)ws;                                 // 4 B
    float* dacc  = (float*)(ws + 4);                           // 4 B
    float* ops   = (float*)(ws + 64);                          // 20 KB
    float* W2    = (float*)(ws + (32 << 10));                  // 1 MB
    unsigned short* envLh  = (unsigned short*)(ws + (4ull << 20));   // 16.8 MB
    unsigned short* Ah     = (unsigned short*)(ws + (21ull << 20));  // 16.8 MB
    unsigned short* Ath    = (unsigned short*)(ws + (38ull << 20));  // 16.8 MB
    unsigned short* envRth = (unsigned short*)(ws + (55ull << 20));  // 16.8 MB
    const size_t big0 = 72ull << 20;

    int Lt = 64;
    while (Lt > 8) {
        size_t need = big0 + 2ull * (size_t)Lt * (1ull << 20);
        if (need <= ws_size) break;
        Lt >>= 1;
    }
    unsigned short* T1 = (unsigned short*)(ws + big0);               // [4][Lt*8][16384]
    unsigned short* Yp = T1 + (size_t)Lt * 524288;                   // [Lt*32][16384]

    const int Lt8 = Lt * 8;
    const int kshiftA = __builtin_ctz(Lt8);                          // G1 k-slab shift
    const long long kextraA = 2097152LL - (long long)Lt8 * 512;
    const int KT = Lt * 512;
    int BKC = KT / 64; if (BKC < 128) BKC = 128;
    const int zk = KT / BKC;
    const int zkShift = __builtin_ctz(zk);

    hipMemsetAsync(ws, 0, 64, stream);

    cast_sumsq<<<1024, 256, 0, stream>>>(A, Ah, 2097152LL, sumsq);
    build_ops<<<1, dim3(32, 32), 0, stream>>>(theta, ops);
    build_w<<<256, dim3(32, 32), 0, stream>>>(coeffs, ops, pref, W2);
    cast_kernel<<<2048, 256, 0, stream>>>(envL, envLh, 2097152LL);
    transpose_cast<<<dim3(512, 16, 1), dim3(32, 8), 0, stream>>>(A, Ath, 512, 16384, 0, 0);
    transpose_cast<<<dim3(128, 16, 4), dim3(32, 8), 0, stream>>>(envR, envRth, 512, 4096,
                                                                 2097152LL, 2097152LL);

    const int ntiles = 512 / Lt;
    for (int t = 0; t < ntiles; ++t) {
        GArg g0, g1;
        // G1: T1[(k,lt,w)][(p,r)] = envL(tile,all k) x Ath^T  [M=4*Lt8, N=16384, K=512]
        g0.A = envLh + (size_t)t * Lt8 * 512; g0.B = Ath; g0.C = T1;
        g0.kshift = kshiftA; g0.kextra = kextraA;
        // G3: Y'[(lt,P)][(k,v,r)] = A(tile) x envRth^T        [M=Lt*32, N=16384, K=512]
        g1.A = Ah + (size_t)t * Lt * 16384; g1.B = envRth; g1.C = Yp;
        g1.kshift = 30; g1.kextra = 0;
        gemm_dual256<<<dim3(64, (Lt * 32) / 256, 2), 512, 0, stream>>>(512, g0, g1);
        // G4: fused-trace contraction over (lt,r), all k
        gemm_g4w<<<dim3(4 * zk), 1024, 0, stream>>>(T1, Yp, W2, dacc, Lt8, zkShift, BKC);
    }
    finalize_kernel<<<1, 64, 0, stream>>>(dacc, sumsq, out);
}

// Round 9
// 1022.892 us; speedup vs baseline: 1.0555x; 1.0555x over previous
//
#include <hip/hip_runtime.h>

// SingleSiteMinimizer, fp16-MFMA pipeline:
//   G1: T1[k][(lt,w)][(p,r)] = envL_k(tile) @ A     } merged dual-grid dispatch
//   G3: Y'[(lt,P)][k*4096+(v,r)] = A(tile) @ envR^T } (blockIdx.z)
//   G4: out += sum_k sum_{m,n} (T1_k Y'_k^T)[m,n] * W2pref[k][n][m]  (fused trace)
//   out /= sum(A^2)
// Round 9: mega-block dual GEMM — grid 256 (1 block/CU), each block computes
// FOUR 256-row panels in a flat 32-iteration double-buffered loop (r7 schedule,
// counted vmcnt(8)); panel epilogues use a separate 17KB LDS region with raw
// s_barrier (no vmcnt drain) so prefetch stays in flight across panels.

typedef __attribute__((ext_vector_type(8))) _Float16 f16x8;
typedef __attribute__((ext_vector_type(4))) float f32x4;

__device__ __forceinline__ unsigned short f2h(float f) {
    _Float16 h = (_Float16)f;
    return *(unsigned short*)&h;
}

__device__ __forceinline__ void gload16(const void* g, void* l) {
    __builtin_amdgcn_global_load_lds(
        (const __attribute__((address_space(1))) void*)g,
        (__attribute__((address_space(3))) void*)l, 16, 0, 0);
}

struct GArg {
    const unsigned short* A;
    const unsigned short* B;
    unsigned short* C;
    int kshift;        // A row slab shift (30 => none)
    long long kextra;  // extra elems per slab
};

// Stage one 256x64 fp16 K-tile of A and B into linear LDS with inverse-swizzled
// global source: LDS slot (r, s) holds global k-chunk s^(r&7)  [rule 21].
__device__ __forceinline__ void stage_tile(
    const GArg& g, int srow0, int col0, int kt0,
    short* dstA, short* dstB, int tid)
{
    #pragma unroll
    for (int q = 0; q < 4; ++q) {
        const int c = q * 512 + tid;
        const int r = c >> 3;
        const int gs = (c & 7) ^ (r & 7);
        const int gr = srow0 + r;
        const size_t aoff = (size_t)gr * 512 + (size_t)((unsigned)gr >> g.kshift) * g.kextra;
        gload16(g.A + aoff + kt0 + gs * 8, dstA + c * 8);
        gload16(g.B + (size_t)(col0 + r) * 512 + kt0 + gs * 8, dstB + c * 8);
    }
}

// ---------- mega dual fp16 GEMM: C[M,N] = Aop[M,K] x Bop[N,K]^T ----------
// K=512. lda=ldb=512, ldc=16384. grid (64, M/1024, 2); 4 row-panels per block.
__global__ __launch_bounds__(512, 1) void gemm_dual_mega(int K, GArg g0, GArg g1)
{
    __shared__ short lds[74240];  // 128KB staging (A0,B0,A1,B1) + 17KB repack
    const GArg g = blockIdx.z ? g1 : g0;
    const int tid = threadIdx.x;
    const int wid = tid >> 6, lane = tid & 63;
    const int wm = wid >> 2, wn = wid & 3;          // 2M x 4N waves
    const int lrow = lane & 15, lgrp = lane >> 4;
    const int sx = lrow & 7;                        // read-side swizzle xor
    const int gsw0 = (lgrp ^ sx) * 8, gsw1 = ((lgrp + 4) ^ sx) * 8;

    // XCD pin: hw linear id % 8 == blockIdx.x % 8 for this grid shape
    const int xcd = blockIdx.x & 7, loc = blockIdx.x >> 3;
    const int col0 = (xcd * 8 + loc) * 256;
    const int row_base = blockIdx.y * 1024;

    short* A0 = lds;          short* B0 = lds + 16384;
    short* A1 = lds + 32768;  short* B1 = lds + 49152;
    short* repk = lds + 65536;                       // 32 x 272 shorts

    const int nt = K >> 6;                           // 8 K-tiles per panel
    const int NT = nt * 4;                           // 32 flat iterations

    f32x4 acc[8][4] = {};

    // prologue: stage it=0,1
    stage_tile(g, row_base, col0, 0, A0, B0, tid);
    stage_tile(g, row_base, col0, 64, A1, B1, tid);
    asm volatile("s_waitcnt vmcnt(8)" ::: "memory");
    __builtin_amdgcn_s_barrier();
    __builtin_amdgcn_sched_barrier(0);

    for (int it = 0; it < NT; ++it) {
        const short* cA = (it & 1) ? A1 : A0;
        const short* cB = (it & 1) ? B1 : B0;
        short* wA = (it & 1) ? A1 : A0;
        short* wB = (it & 1) ? B1 : B0;

        f16x8 bfr[4][2], afr[4][2];
        #pragma unroll
        for (int j = 0; j < 4; ++j) {
            const int R = wn * 64 + j * 16 + lrow;
            bfr[j][0] = *(const f16x8*)&cB[R * 64 + gsw0];
            bfr[j][1] = *(const f16x8*)&cB[R * 64 + gsw1];
        }
        #pragma unroll
        for (int i = 0; i < 4; ++i) {
            const int R = wm * 128 + i * 16 + lrow;
            afr[i][0] = *(const f16x8*)&cA[R * 64 + gsw0];
            afr[i][1] = *(const f16x8*)&cA[R * 64 + gsw1];
        }
        __builtin_amdgcn_s_setprio(1);
        #pragma unroll
        for (int i = 0; i < 4; ++i)
            #pragma unroll
            for (int j = 0; j < 4; ++j) {
                acc[i][j] = __builtin_amdgcn_mfma_f32_16x16x32_f16(afr[i][0], bfr[j][0], acc[i][j], 0, 0, 0);
                acc[i][j] = __builtin_amdgcn_mfma_f32_16x16x32_f16(afr[i][1], bfr[j][1], acc[i][j], 0, 0, 0);
            }
        __builtin_amdgcn_s_setprio(0);
        // phase-2 A fragments (rows 64..127 of the wave's M-half)
        #pragma unroll
        for (int i = 0; i < 4; ++i) {
            const int R = wm * 128 + (i + 4) * 16 + lrow;
            afr[i][0] = *(const f16x8*)&cA[R * 64 + gsw0];
            afr[i][1] = *(const f16x8*)&cA[R * 64 + gsw1];
        }
        asm volatile("s_waitcnt lgkmcnt(0)" ::: "memory");
        __builtin_amdgcn_sched_barrier(0);
        __builtin_amdgcn_s_barrier();               // all reads of buf[it&1] retired
        __builtin_amdgcn_sched_barrier(0);
        if (it + 2 < NT) {
            const int it2 = it + 2;
            stage_tile(g, row_base + (it2 >> 3) * 256, col0, (it2 & 7) * 64, wA, wB, tid);
        }
        __builtin_amdgcn_s_setprio(1);
        #pragma unroll
        for (int i = 0; i < 4; ++i)
            #pragma unroll
            for (int j = 0; j < 4; ++j) {
                acc[i + 4][j] = __builtin_amdgcn_mfma_f32_16x16x32_f16(afr[i][0], bfr[j][0], acc[i + 4][j], 0, 0, 0);
                acc[i + 4][j] = __builtin_amdgcn_mfma_f32_16x16x32_f16(afr[i][1], bfr[j][1], acc[i + 4][j], 0, 0, 0);
            }
        __builtin_amdgcn_s_setprio(0);
        __builtin_amdgcn_sched_barrier(0);
        if (it + 2 < NT) asm volatile("s_waitcnt vmcnt(8)" ::: "memory");  // it+1 landed
        else             asm volatile("s_waitcnt vmcnt(0)" ::: "memory");  // tail drain
        __builtin_amdgcn_sched_barrier(0);
        __builtin_amdgcn_s_barrier();
        __builtin_amdgcn_sched_barrier(0);

        // ---- panel boundary: write this panel's C, reset acc. Raw barriers only
        // (no __syncthreads: must not drain the in-flight prefetch vmcnt).
        if ((it & 7) == 7) {
            const int row0 = row_base + (it >> 3) * 256;
            const int orow = lgrp * 4, ocol = lrow;
            #pragma unroll
            for (int c8 = 0; c8 < 8; ++c8) {        // 32-row chunks
                if (wm == (c8 >> 2)) {
                    const int ib = (c8 & 3) * 2;
                    #pragma unroll
                    for (int di = 0; di < 2; ++di)
                        #pragma unroll
                        for (int j = 0; j < 4; ++j)
                            #pragma unroll
                            for (int q = 0; q < 4; ++q)
                                repk[(di * 16 + orow + q) * 272 + wn * 64 + j * 16 + ocol] =
                                    (short)f2h(acc[ib + di][j][q]);
                }
                asm volatile("s_waitcnt lgkmcnt(0)" ::: "memory");
                __builtin_amdgcn_s_barrier();
                #pragma unroll
                for (int s2 = 0; s2 < 2; ++s2) {
                    const int idx = s2 * 512 + tid;
                    const int rr = idx >> 5, cc = idx & 31;
                    *(int4*)(g.C + (size_t)(row0 + c8 * 32 + rr) * 16384 + col0 + cc * 8) =
                        *(const int4*)&repk[rr * 272 + cc * 8];
                }
                asm volatile("s_waitcnt lgkmcnt(0)" ::: "memory");
                __builtin_amdgcn_s_barrier();
            }
            #pragma unroll
            for (int i = 0; i < 8; ++i)
                #pragma unroll
                for (int j = 0; j < 4; ++j)
                    acc[i][j] = (f32x4){0.f, 0.f, 0.f, 0.f};
        }
    }
}

// ---------- G4: 1024-thread blocks, full 256x256 output, exactly-once reads ----------
__global__ __launch_bounds__(1024) void gemm_g4w(
    const unsigned short* __restrict__ T1, const unsigned short* __restrict__ Yp,
    const float* __restrict__ W2p, float* __restrict__ dacc,
    int Lt8, int zkShift, int BKC)
{
    __shared__ short sh[16384];  // As = sh[0:8192], Bs = sh[8192:16384]
    const int tid = threadIdx.x;
    const int wid = tid >> 6, lane = tid & 63;
    const int kidx = blockIdx.x >> zkShift;
    const int kz = (blockIdx.x - (kidx << zkShift)) * BKC;
    const int wr = (wid >> 2) * 64, wc = (wid & 3) * 64;
    const int lrow = lane & 15, kb = (lane >> 4) * 8;

    const int r = tid >> 2, kc = (tid & 3) * 8;  // staging: row 0..255
    const int w_ = r >> 5, p_ = r & 31;
    const size_t T1k = (size_t)kidx * Lt8 * 16384;
    const size_t Yk = (size_t)kidx * 4096;
    const size_t aoff = T1k + (size_t)w_ * 16384 + (size_t)p_ * 512;   // + lt*131072 + rr
    const size_t boff = Yk + (size_t)p_ * 16384 + (size_t)w_ * 512;    // (v=w_, P=p_)

    f32x4 acc[4][4] = {};

    for (int k0 = 0; k0 < BKC; k0 += 32) {
        const int kk = kz + k0;
        const int lt = kk >> 9, rbase = kk & 511;
        gload16(T1 + aoff + (size_t)lt * 131072 + rbase + kc, sh + tid * 8);
        gload16(Yp + boff + (size_t)lt * 524288 + rbase + kc, sh + 8192 + tid * 8);
        __syncthreads();
        f16x8 a[4], b[4];
        #pragma unroll
        for (int i = 0; i < 4; ++i)
            a[i] = *(const f16x8*)&sh[(wr + i * 16 + lrow) * 32 + kb];
        #pragma unroll
        for (int j = 0; j < 4; ++j)
            b[j] = *(const f16x8*)&sh[8192 + (wc + j * 16 + lrow) * 32 + kb];
        #pragma unroll
        for (int i = 0; i < 4; ++i)
            #pragma unroll
            for (int j = 0; j < 4; ++j)
                acc[i][j] = __builtin_amdgcn_mfma_f32_16x16x32_f16(a[i], b[j], acc[i][j], 0, 0, 0);
        __syncthreads();
    }

    // fused weighted trace
    const int orow = (lane >> 4) * 4, ocol = lane & 15;
    const float* Wk = W2p + ((size_t)kidx << 16);
    float s = 0.f;
    #pragma unroll
    for (int j = 0; j < 4; ++j) {
        const int n = wc + j * 16 + ocol;
        const float* wrow = Wk + (size_t)n * 256 + wr + orow;
        #pragma unroll
        for (int i = 0; i < 4; ++i) {
            float4 wv = *(const float4*)(wrow + i * 16);
            s += wv.x * acc[i][j][0] + wv.y * acc[i][j][1]
               + wv.z * acc[i][j][2] + wv.w * acc[i][j][3];
        }
    }
    __syncthreads();
    float* red = (float*)sh;
    red[tid] = s;
    __syncthreads();
    for (int st = 512; st > 0; st >>= 1) {
        if (tid < st) red[tid] += red[tid + st];
        __syncthreads();
    }
    if (tid == 0) atomicAdd(dacc, red[0]);
}

// ---------- prep kernels ----------
__global__ __launch_bounds__(256) void cast_sumsq(
    const float* __restrict__ in, unsigned short* __restrict__ out,
    long long n4, float* __restrict__ sumsq)
{
    float p = 0.f;
    for (long long i = (long long)blockIdx.x * blockDim.x + threadIdx.x; i < n4;
         i += (long long)gridDim.x * blockDim.x) {
        float4 v = ((const float4*)in)[i];
        p += v.x * v.x + v.y * v.y + v.z * v.z + v.w * v.w;
        union { unsigned short s[4]; uint2 d; } o;
        o.s[0] = f2h(v.x); o.s[1] = f2h(v.y); o.s[2] = f2h(v.z); o.s[3] = f2h(v.w);
        ((uint2*)out)[i] = o.d;
    }
    __shared__ float sh[256];
    sh[threadIdx.x] = p;
    __syncthreads();
    for (int s = 128; s > 0; s >>= 1) {
        if (threadIdx.x < s) sh[threadIdx.x] += sh[threadIdx.x + s];
        __syncthreads();
    }
    if (threadIdx.x == 0) atomicAdd(sumsq, sh[0]);
}

__global__ void cast_kernel(const float* __restrict__ in, unsigned short* __restrict__ out,
                            long long n4)
{
    for (long long i = (long long)blockIdx.x * blockDim.x + threadIdx.x; i < n4;
         i += (long long)gridDim.x * blockDim.x) {
        float4 v = ((const float4*)in)[i];
        union { unsigned short s[4]; uint2 d; } o;
        o.s[0] = f2h(v.x); o.s[1] = f2h(v.y); o.s[2] = f2h(v.z); o.s[3] = f2h(v.w);
        ((uint2*)out)[i] = o.d;
    }
}

__global__ void transpose_cast(const float* __restrict__ in, unsigned short* __restrict__ out,
                               int R, int C, long long in_stride, long long out_stride)
{
    __shared__ float tile[32][33];
    in += (long long)blockIdx.z * in_stride;
    out += (long long)blockIdx.z * out_stride;
    int c0 = blockIdx.x * 32, r0 = blockIdx.y * 32;
    int tx = threadIdx.x, ty = threadIdx.y;  // (32, 8)
    #pragma unroll
    for (int i = 0; i < 4; ++i)
        tile[ty + i * 8][tx] = in[(size_t)(r0 + ty + i * 8) * C + c0 + tx];
    __syncthreads();
    #pragma unroll
    for (int i = 0; i < 4; ++i)
        out[(size_t)(c0 + ty + i * 8) * R + r0 + tx] = f2h(tile[tx][ty + i * 8]);
}

__global__ void build_ops(const float* __restrict__ theta, float* __restrict__ ops)
{
    __shared__ float X[32][32], Pm[32][32];
    int i = threadIdx.y, j = threadIdx.x;
    float c = cosf(theta[0]), s = sinf(theta[0]);
    float aij = (j == i + 1) ? sqrtf((float)j) : 0.f;
    float aji = (i == j + 1) ? sqrtf((float)i) : 0.f;
    const float inv = 0.70710678118654752440f;
    float x0 = (aij + aji) * inv;
    float p0 = (aij - aji) * inv;
    X[i][j] = c * x0 + s * p0;
    Pm[i][j] = -s * x0 + c * p0;
    __syncthreads();
    float xx = 0.f, pp = 0.f;
    #pragma unroll
    for (int m = 0; m < 32; ++m) {
        xx += X[i][m] * X[m][j];
        pp += Pm[i][m] * Pm[m][j];
    }
    ops[0 * 1024 + i * 32 + j] = (i == j) ? 1.f : 0.f;
    ops[1 * 1024 + i * 32 + j] = X[i][j];
    ops[2 * 1024 + i * 32 + j] = Pm[i][j];
    ops[3 * 1024 + i * 32 + j] = xx;
    ops[4 * 1024 + i * 32 + j] = pp;
}

// W2p[k][(v*32+P)*256 + (w*32+p)] = pref[k] * sum_c coeffs[k,w,v,c] * ops[c][P,p]
__global__ void build_w(const float* __restrict__ coeffs, const float* __restrict__ ops,
                        const float* __restrict__ pref, float* __restrict__ W2)
{
    int b = blockIdx.x;  // (k,w,v)
    int k = b >> 6, w = (b >> 3) & 7, v = b & 7;
    int P = threadIdx.y, p = threadIdx.x;
    const float* cf = coeffs + ((k * 8 + w) * 8 + v) * 5;
    float acc = 0.f;
    #pragma unroll
    for (int c = 0; c < 5; ++c) acc += cf[c] * ops[c * 1024 + P * 32 + p];
    W2[(size_t)k * 65536 + (v * 32 + P) * 256 + (w * 32 + p)] = acc * pref[k];
}

__global__ void finalize_kernel(const float* __restrict__ dacc, const float* __restrict__ sumsq,
                                float* __restrict__ out)
{
    if (threadIdx.x == 0) out[0] = dacc[0] / sumsq[0];
}

extern "C" void kernel_launch(void* const* d_in, const int* in_sizes, int n_in,
                              void* d_out, int out_size, void* d_ws, size_t ws_size,
                              hipStream_t stream)
{
    const float* A      = (const float*)d_in[0];  // [512,32,512]
    const float* theta  = (const float*)d_in[1];
    const float* envL   = (const float*)d_in[2];  // [4,512,8,512]
    const float* envR   = (const float*)d_in[3];  // [4,512,8,512]
    const float* coeffs = (const float*)d_in[4];  // [4,8,8,5]
    const float* pref   = (const float*)d_in[5];  // [4]
    float* out = (float*)d_out;

    char* ws = (char*)d_ws;
    float* sumsq = (float*)ws;                                 // 4 B
    float* dacc  = (float*)(ws + 4);                           // 4 B
    float* ops   = (float*)(ws + 64);                          // 20 KB
    float* W2    = (float*)(ws + (32 << 10));                  // 1 MB
    unsigned short* envLh  = (unsigned short*)(ws + (4ull << 20));   // 16.8 MB
    unsigned short* Ah     = (unsigned short*)(ws + (21ull << 20));  // 16.8 MB
    unsigned short* Ath    = (unsigned short*)(ws + (38ull << 20));  // 16.8 MB
    unsigned short* envRth = (unsigned short*)(ws + (55ull << 20));  // 16.8 MB
    const size_t big0 = 72ull << 20;

    int Lt = 64;
    while (Lt > 32) {
        size_t need = big0 + 2ull * (size_t)Lt * (1ull << 20);
        if (need <= ws_size) break;
        Lt >>= 1;
    }
    unsigned short* T1 = (unsigned short*)(ws + big0);               // [4][Lt*8][16384]
    unsigned short* Yp = T1 + (size_t)Lt * 524288;                   // [Lt*32][16384]

    const int Lt8 = Lt * 8;
    const int kshiftA = __builtin_ctz(Lt8);                          // G1 k-slab shift
    const long long kextraA = 2097152LL - (long long)Lt8 * 512;
    const int KT = Lt * 512;
    int BKC = KT / 64; if (BKC < 128) BKC = 128;
    const int zk = KT / BKC;
    const int zkShift = __builtin_ctz(zk);

    hipMemsetAsync(ws, 0, 64, stream);

    cast_sumsq<<<1024, 256, 0, stream>>>(A, Ah, 2097152LL, sumsq);
    build_ops<<<1, dim3(32, 32), 0, stream>>>(theta, ops);
    build_w<<<256, dim3(32, 32), 0, stream>>>(coeffs, ops, pref, W2);
    cast_kernel<<<2048, 256, 0, stream>>>(envL, envLh, 2097152LL);
    transpose_cast<<<dim3(512, 16, 1), dim3(32, 8), 0, stream>>>(A, Ath, 512, 16384, 0, 0);
    transpose_cast<<<dim3(128, 16, 4), dim3(32, 8), 0, stream>>>(envR, envRth, 512, 4096,
                                                                 2097152LL, 2097152LL);

    const int ntiles = 512 / Lt;
    for (int t = 0; t < ntiles; ++t) {
        GArg g0, g1;
        // G1: T1[(k,lt,w)][(p,r)] = envL(tile,all k) x Ath^T  [M=4*Lt8, N=16384, K=512]
        g0.A = envLh + (size_t)t * Lt8 * 512; g0.B = Ath; g0.C = T1;
        g0.kshift = kshiftA; g0.kextra = kextraA;
        // G3: Y'[(lt,P)][(k,v,r)] = A(tile) x envRth^T        [M=Lt*32, N=16384, K=512]
        g1.A = Ah + (size_t)t * Lt * 16384; g1.B = envRth; g1.C = Yp;
        g1.kshift = 30; g1.kextra = 0;
        gemm_dual_mega<<<dim3(64, (Lt * 32) / 1024, 2), 512, 0, stream>>>(512, g0, g1);
        // G4: fused-trace contraction over (lt,r), all k
        gemm_g4w<<<dim3(4 * zk), 1024, 0, stream>>>(T1, Yp, W2, dacc, Lt8, zkShift, BKC);
    }
    finalize_kernel<<<1, 64, 0, stream>>>(dacc, sumsq, out);
}